// Round 6
// baseline (263.142 us; speedup 1.0000x reference)
//
#include <hip/hip_runtime.h>
#include <stdint.h>

typedef unsigned short u16;
typedef __attribute__((ext_vector_type(8))) short bf16x8;
typedef __attribute__((ext_vector_type(4))) float f32x4;

#define MFMA(a,b,c) __builtin_amdgcn_mfma_f32_16x16x32_bf16((a),(b),(c),0,0,0)

static constexpr int S  = 4096;
static constexpr int D  = 768;
static constexpr int H  = 12;
static constexpr int HD = 64;

// float -> bf16 round-nearest-even
__device__ __forceinline__ u16 f2b(float f){
  union { float f; unsigned u; } v; v.f = f;
  unsigned r = (v.u + 0x7fffu + ((v.u >> 16) & 1u)) >> 16;
  return (u16)r;
}

// pack 2 floats -> 2 bf16 (truncation) in ONE v_perm_b32
__device__ __forceinline__ unsigned pack_bf16_trunc(float a, float b){
  return __builtin_amdgcn_perm(__float_as_uint(b), __float_as_uint(a), 0x07060302u);
}

// async global->LDS 16B per lane (DMA path) -- used by the GEMMs only
__device__ __forceinline__ void cp16(const u16* g, u16* l){
  __builtin_amdgcn_global_load_lds(
      (const __attribute__((address_space(1))) unsigned int*)g,
      (__attribute__((address_space(3))) unsigned int*)l, 16, 0, 0);
}

// 4-lane (quad) butterfly transpose via gfx950 permlane swaps (4 VALU instrs).
__device__ __forceinline__ bf16x8 quad_transpose(unsigned M0, unsigned M1,
                                                 unsigned M2, unsigned M3){
  auto r0 = __builtin_amdgcn_permlane32_swap(M0, M2, false, false);
  auto r1 = __builtin_amdgcn_permlane32_swap(M1, M3, false, false);
  auto s0 = __builtin_amdgcn_permlane16_swap(r0[0], r0[1], false, false);
  auto s1 = __builtin_amdgcn_permlane16_swap(r1[0], r1[1], false, false);
  union { unsigned u[4]; bf16x8 v; } r;
  r.u[0] = s0[0];
  r.u[1] = s1[0];
  r.u[2] = s0[1];
  r.u[3] = s1[1];
  return r.v;
}

// ---------------- fused cast fp32 -> bf16 for x + 4 weights ----------------
static constexpr int NX4 = (2 * S * D) / 4;   // 1572864
static constexpr int NW4 = (D * D) / 4;       // 147456
__global__ void castall(const float* __restrict__ x,  const float* __restrict__ wq,
                        const float* __restrict__ wk, const float* __restrict__ wv,
                        const float* __restrict__ wo,
                        u16* __restrict__ xb,  u16* __restrict__ wqb,
                        u16* __restrict__ wkb, u16* __restrict__ wvb,
                        u16* __restrict__ wob){
  int i = blockIdx.x * 256 + threadIdx.x;
  const float* s; u16* d; int off;
  if (i < NX4) { s = x; d = xb; off = i; }
  else {
    int j = i - NX4; int wsel = j / NW4; off = j - wsel * NW4;
    if (wsel >= 4) return;
    s = (wsel == 0) ? wq : (wsel == 1) ? wk : (wsel == 2) ? wv : wo;
    d = (wsel == 0) ? wqb : (wsel == 1) ? wkb : (wsel == 2) ? wvb : wob;
  }
  float4 v = ((const float4*)s)[off];
  uint2 o;
  o.x = (unsigned)f2b(v.x) | ((unsigned)f2b(v.y) << 16);
  o.y = (unsigned)f2b(v.z) | ((unsigned)f2b(v.w) << 16);
  ((uint2*)d)[off] = o;
}

// ---------------- QKV GEMM (m97 pattern): BK=64, global_load_lds staging, XOR-swizzled LDS.
__global__ __launch_bounds__(256, 2) void qkv_gemm(
    const u16* __restrict__ xb, const u16* __restrict__ wq, const u16* __restrict__ wk,
    const u16* __restrict__ wv, u16* __restrict__ Qb, u16* __restrict__ Kb, u16* __restrict__ Vt)
{
  __shared__ __align__(16) u16 As[128 * 64];
  __shared__ __align__(16) u16 Bs[128 * 64];
  const int t = threadIdx.x;
  const int mblk = blockIdx.x, nblk = blockIdx.y, z = blockIdx.z;
  const u16* W = (z == 0) ? wq : (z == 1) ? wk : wv;
  const int w = t >> 6, lane = t & 63, quad = lane >> 4, l16 = lane & 15;
  const int wr = w >> 1, wc = w & 1;
  const int l7 = l16 & 7;

  f32x4 acc[4][4];
  #pragma unroll
  for (int i = 0; i < 4; i++)
    #pragma unroll
    for (int j = 0; j < 4; j++) acc[i][j] = (f32x4){0.f, 0.f, 0.f, 0.f};

  int srow[4], schk[4];
  #pragma unroll
  for (int i = 0; i < 4; i++) {
    int s = i * 256 + t;
    srow[i] = s >> 3;
    schk[i] = (s & 7) ^ (srow[i] & 7);
  }
  const u16* gA = xb + (size_t)(mblk * 128) * D;
  const u16* gB = W  + (size_t)(nblk * 128) * D;

  for (int k0 = 0; k0 < D; k0 += 64) {
    __syncthreads();
    #pragma unroll
    for (int i = 0; i < 4; i++) {
      int s = i * 256 + t;
      cp16(gA + (size_t)srow[i] * D + k0 + schk[i] * 8, As + s * 8);
      cp16(gB + (size_t)srow[i] * D + k0 + schk[i] * 8, Bs + s * 8);
    }
    __syncthreads();
    #pragma unroll
    for (int j = 0; j < 2; j++) {
      bf16x8 af[4], bfr[4];
      #pragma unroll
      for (int mt = 0; mt < 4; mt++)
        af[mt]  = *(const bf16x8*)(As + (wr * 64 + mt * 16 + l16) * 64 + ((j * 4 + quad) ^ l7) * 8);
      #pragma unroll
      for (int nt = 0; nt < 4; nt++)
        bfr[nt] = *(const bf16x8*)(Bs + (wc * 64 + nt * 16 + l16) * 64 + ((j * 4 + quad) ^ l7) * 8);
      #pragma unroll
      for (int mt = 0; mt < 4; mt++)
        #pragma unroll
        for (int nt = 0; nt < 4; nt++)
          acc[mt][nt] = MFMA(af[mt], bfr[nt], acc[mt][nt]);
    }
  }

  const float qscale = 0.18033688011112042f;  // 0.125 * log2(e)
  #pragma unroll
  for (int mt = 0; mt < 4; mt++) {
    int m0 = mblk * 128 + wr * 64 + mt * 16 + quad * 4;
    #pragma unroll
    for (int nt = 0; nt < 4; nt++) {
      int n = nblk * 128 + wc * 64 + nt * 16 + l16;
      int h = n >> 6, hd = n & 63;
      if (z == 2) {
        int b = m0 >> 12, s0 = m0 & 4095;
        u16* p = Vt + (((size_t)(b * H + h) * HD + hd)) * S + s0;
        uint2 pk;
        pk.x = (unsigned)f2b(acc[mt][nt][0]) | ((unsigned)f2b(acc[mt][nt][1]) << 16);
        pk.y = (unsigned)f2b(acc[mt][nt][2]) | ((unsigned)f2b(acc[mt][nt][3]) << 16);
        *(uint2*)p = pk;
      } else {
        u16* dst = (z == 0) ? Qb : Kb;
        float sc = (z == 0) ? qscale : 1.0f;
        #pragma unroll
        for (int r = 0; r < 4; r++) {
          int m = m0 + r; int b = m >> 12, s = m & 4095;
          dst[((size_t)(b * H + h) * S + s) * HD + hd] = f2b(acc[mt][nt][r] * sc);
        }
      }
    }
  }
}

// ---------------- flash attention, barrier-free (direct-from-L2) ----------------
// R5 post-mortem: 45 of 82.5us was stall; the only block-wide serializer is the per-iter
// staging barrier pair + vmcnt(0) drain. K/V per bh = 1MB -> L2-resident (FETCH stayed
// 20MB), and each wave reads only its own 8KB K-half + 8KB V-half whose MFMA fragments
// (16 rows x 16B/lane) load directly from global. So: NO LDS staging, NO barriers in the
// kv-loop -- each wave issues its own global 16B loads (L2 hits), compiler pipelines
// across iterations, waves drift freely. LDS is epilogue-only (32KB cross-wave O reduce).
// Wave split unchanged: 2x2 of 64q x 64k, in-register P^T via permlane transpose.
// grid: 768 blocks, R5 snake mapping (keeps 3 bhs/XCD -> L2 locality + CU balance).
__global__ __launch_bounds__(256, 2) void attn(
    const u16* __restrict__ Qb, const u16* __restrict__ Kb,
    const u16* __restrict__ Vt, u16* __restrict__ ctx)
{
  __shared__ float Red[2][4096];                // 32KB epilogue O exchange ([wq][16 frag rows x 64 lanes x 4])
  __shared__ float Lbuf[2][4][16];              // lsum exchange: [wq][qt][l16]
  const int t = threadIdx.x, w = t >> 6, lane = t & 63, quad = lane >> 4, l16 = lane & 15;
  const int wq = w >> 1, wk = w & 1;            // query-half, key-half of this wave

  // ---- balanced XCD-local unit mapping (R5 snake) ----
  const int p   = (int)blockIdx.x;
  const int xcd = p & 7;
  const int loc = p >> 3;
  const int r_  = loc >> 5, j_ = loc & 31;
  const int u   = (r_ == 0) ? j_ : (r_ == 1) ? (63 - j_) : (64 + j_);
  const int qtile = 31 - u / 3;
  const int bh    = xcd + 8 * (u % 3);

  const int q0 = qtile * 128;
  const u16* Qh = Qb + (size_t)bh * S * HD;
  const u16* Kh = Kb + (size_t)bh * S * HD;
  const u16* Vh = Vt + (size_t)bh * S * HD;     // [64][4096]
  const int b = bh / H, h = bh % H;

  // Q fragments (B-operand): lane holds Q[q0+wq*64+qt*16+l16][ksh*32+quad*8 ..+7]
  bf16x8 qf[4][2];
  #pragma unroll
  for (int qt = 0; qt < 4; qt++)
    #pragma unroll
    for (int ksh = 0; ksh < 2; ksh++)
      qf[qt][ksh] = *(const bf16x8*)(Qh + (size_t)(q0 + wq * 64 + qt * 16 + l16) * HD + ksh * 32 + quad * 8);

  // O^T acc: row=hd (co*16+quad*4+r), col=query (qt*16+l16); partial over this wave's keys
  f32x4 ao[4][4];
  #pragma unroll
  for (int qt = 0; qt < 4; qt++)
    #pragma unroll
    for (int co = 0; co < 4; co++) ao[qt][co] = (f32x4){0.f, 0.f, 0.f, 0.f};
  float lsum[4] = {0.f, 0.f, 0.f, 0.f};         // per-lane partial denominators, query qt*16+l16

  for (int kv0 = 0; kv0 <= q0; kv0 += 128) {
    const bool diag = (kv0 == q0);
    if (diag && (wk > wq)) break;               // diag is the last iter; this wave has no work
    const bool mdiag = diag && (wk == wq);      // element-mask region

    // this wave's 64-key slice, straight from global (L2-resident)
    const u16* Kt = Kh + (size_t)(kv0 + wk * 64) * HD;   // [64 keys][64 hd]
    const u16* Vs = Vh + kv0 + wk * 64;                  // [64 hd][*] cols of V^T

    #pragma unroll
    for (int g = 0; g < 2; g++) {               // 32-key groups within this wave's 64 keys
      unsigned pA[4][2], pB[4][2];              // [qt][ktL]: packed bf16 pairs
      #pragma unroll
      for (int ktL = 0; ktL < 2; ktL++) {
        const int kt = g * 2 + ktL;             // 16-key tile index within 64
        const u16* kr = Kt + (size_t)(kt * 16 + l16) * HD + quad * 8;
        bf16x8 kf0 = *(const bf16x8*)(kr);       // hd  0..31 slice (quad*8)
        bf16x8 kf1 = *(const bf16x8*)(kr + 32);  // hd 32..63 slice
        #pragma unroll
        for (int qt = 0; qt < 4; qt++) {
          f32x4 s0 = (f32x4){0.f, 0.f, 0.f, 0.f};
          s0 = MFMA(kf0, qf[qt][0], s0);
          s0 = MFMA(kf1, qf[qt][1], s0);
          if (mdiag) {
            // key_rel = kt*16+quad*4+r, query_rel = qt*16+l16; mask key>query
            const int qoff = (qt - kt) * 16 + l16;
            #pragma unroll
            for (int r = 0; r < 4; r++)
              s0[r] = (quad * 4 + r > qoff) ? -1e30f : s0[r];
          }
          float p0 = __builtin_amdgcn_exp2f(s0[0]);
          float p1 = __builtin_amdgcn_exp2f(s0[1]);
          float p2 = __builtin_amdgcn_exp2f(s0[2]);
          float p3 = __builtin_amdgcn_exp2f(s0[3]);
          lsum[qt] += (p0 + p1) + (p2 + p3);
          pA[qt][ktL] = pack_bf16_trunc(p0, p1);
          pB[qt][ktL] = pack_bf16_trunc(p2, p3);
        }
      }
      // in-register P^T fragments for this 32-key group
      bf16x8 pf[4];
      #pragma unroll
      for (int qt = 0; qt < 4; qt++)
        pf[qt] = quad_transpose(pA[qt][0], pB[qt][0], pA[qt][1], pB[qt][1]);
      // O^T += V^T P^T  (V fragments straight from global)
      #pragma unroll
      for (int co = 0; co < 4; co++) {
        bf16x8 vf = *(const bf16x8*)(Vs + (size_t)(co * 16 + l16) * S + g * 32 + quad * 8);
        #pragma unroll
        for (int qt = 0; qt < 4; qt++)
          ao[qt][co] = MFMA(vf, pf[qt], ao[qt][co]);
      }
    }
  }

  // ---- epilogue: quad-reduce lsum, then cross-wave (wk) reduction of O and lsum ----
  #pragma unroll
  for (int qt = 0; qt < 4; qt++) {
    float v = lsum[qt];
    v += __shfl_xor(v, 16, 64);
    v += __shfl_xor(v, 32, 64);
    lsum[qt] = v;
  }

  float* red = &Red[wq][0];
  if (wk == 1) {
    #pragma unroll
    for (int qt = 0; qt < 4; qt++)
      #pragma unroll
      for (int co = 0; co < 4; co++)
        *(f32x4*)(red + ((qt * 4 + co) * 64 + lane) * 4) = ao[qt][co];
    if (lane < 16) {
      #pragma unroll
      for (int qt = 0; qt < 4; qt++) Lbuf[wq][qt][lane] = lsum[qt];
    }
  }
  __syncthreads();
  if (wk == 0) {
    #pragma unroll
    for (int qt = 0; qt < 4; qt++) {
      float tot = lsum[qt] + Lbuf[wq][qt][l16];
      float inv = 1.0f / tot;
      int token = b * S + q0 + wq * 64 + qt * 16 + l16;
      #pragma unroll
      for (int co = 0; co < 4; co++) {
        f32x4 pr = *(const f32x4*)(red + ((qt * 4 + co) * 64 + lane) * 4);
        f32x4 sv = ao[qt][co] + pr;
        uint2 pk;
        pk.x = (unsigned)f2b(sv[0] * inv) | ((unsigned)f2b(sv[1] * inv) << 16);
        pk.y = (unsigned)f2b(sv[2] * inv) | ((unsigned)f2b(sv[3] * inv) << 16);
        *(uint2*)(ctx + (size_t)token * D + h * HD + co * 16 + quad * 4) = pk;
      }
    }
  }
}

// ---------------- output projection (m97 pattern): ctx[8192,768] x Wo^T + bias -> fp32 out
__global__ __launch_bounds__(256, 2) void out_gemm(
    const u16* __restrict__ ctx, const u16* __restrict__ wo,
    const float* __restrict__ bias, float* __restrict__ out)
{
  __shared__ __align__(16) u16 As[128 * 64];
  __shared__ __align__(16) u16 Bs[128 * 64];
  const int t = threadIdx.x;
  const int mblk = blockIdx.x, nblk = blockIdx.y;
  const int w = t >> 6, lane = t & 63, quad = lane >> 4, l16 = lane & 15;
  const int wr = w >> 1, wc = w & 1;
  const int l7 = l16 & 7;

  f32x4 acc[4][4];
  #pragma unroll
  for (int i = 0; i < 4; i++)
    #pragma unroll
    for (int j = 0; j < 4; j++) acc[i][j] = (f32x4){0.f, 0.f, 0.f, 0.f};

  int srow[4], schk[4];
  #pragma unroll
  for (int i = 0; i < 4; i++) {
    int s = i * 256 + t;
    srow[i] = s >> 3;
    schk[i] = (s & 7) ^ (srow[i] & 7);
  }
  const u16* gA = ctx + (size_t)(mblk * 128) * D;
  const u16* gB = wo  + (size_t)(nblk * 128) * D;

  for (int k0 = 0; k0 < D; k0 += 64) {
    __syncthreads();
    #pragma unroll
    for (int i = 0; i < 4; i++) {
      int s = i * 256 + t;
      cp16(gA + (size_t)srow[i] * D + k0 + schk[i] * 8, As + s * 8);
      cp16(gB + (size_t)srow[i] * D + k0 + schk[i] * 8, Bs + s * 8);
    }
    __syncthreads();
    #pragma unroll
    for (int j = 0; j < 2; j++) {
      bf16x8 af[4], bfr[4];
      #pragma unroll
      for (int mt = 0; mt < 4; mt++)
        af[mt]  = *(const bf16x8*)(As + (wr * 64 + mt * 16 + l16) * 64 + ((j * 4 + quad) ^ l7) * 8);
      #pragma unroll
      for (int nt = 0; nt < 4; nt++)
        bfr[nt] = *(const bf16x8*)(Bs + (wc * 64 + nt * 16 + l16) * 64 + ((j * 4 + quad) ^ l7) * 8);
      #pragma unroll
      for (int mt = 0; mt < 4; mt++)
        #pragma unroll
        for (int nt = 0; nt < 4; nt++)
          acc[mt][nt] = MFMA(af[mt], bfr[nt], acc[mt][nt]);
    }
  }

  #pragma unroll
  for (int mt = 0; mt < 4; mt++) {
    int m0 = mblk * 128 + wr * 64 + mt * 16 + quad * 4;
    #pragma unroll
    for (int nt = 0; nt < 4; nt++) {
      int n = nblk * 128 + wc * 64 + nt * 16 + l16;
      float bv = bias[n];
      #pragma unroll
      for (int r = 0; r < 4; r++)
        out[(size_t)(m0 + r) * D + n] = acc[mt][nt][r] + bv;
    }
  }
}

// ---------------- host launch ----------------
extern "C" void kernel_launch(void* const* d_in, const int* in_sizes, int n_in,
                              void* d_out, int out_size, void* d_ws, size_t ws_size,
                              hipStream_t stream) {
  const float* x    = (const float*)d_in[0];
  const float* wq   = (const float*)d_in[1];
  const float* wk   = (const float*)d_in[2];
  const float* wv   = (const float*)d_in[3];
  const float* wo   = (const float*)d_in[4];
  const float* bo   = (const float*)d_in[5];
  float* out = (float*)d_out;

  u16* ws = (u16*)d_ws;
  const size_t NX = (size_t)2 * S * D;      // 6291456
  const size_t NW = (size_t)D * D;          // 589824
  u16* xb  = ws;                // [8192][768]; reused as ctx after qkv_gemm consumes it
  u16* wqb = ws + NX;
  u16* wkb = wqb + NW;
  u16* wvb = wkb + NW;
  u16* wob = wvb + NW;
  u16* Qb  = wob + NW;          // [2][12][4096][64] bf16 (pre-scaled by 0.125*log2e)
  u16* Kb  = Qb + NX;           // bf16
  u16* Vt  = Kb + NX;           // [2][12][64][4096] bf16
  u16* ctx = xb;

  const int total4 = NX4 + 4 * NW4;
  castall<<<(total4 + 255) / 256, 256, 0, stream>>>(x, wq, wk, wv, wo, xb, wqb, wkb, wvb, wob);

  qkv_gemm<<<dim3(64, 6, 3), 256, 0, stream>>>(xb, wqb, wkb, wvb, Qb, Kb, Vt);
  attn<<<dim3(768), 256, 0, stream>>>(Qb, Kb, Vt, ctx);
  out_gemm<<<dim3(64, 6), 256, 0, stream>>>(ctx, wob, bo, out);
}

// Round 7
// 215.427 us; speedup vs baseline: 1.2215x; 1.2215x over previous
//
#include <hip/hip_runtime.h>
#include <stdint.h>

typedef unsigned short u16;
typedef __attribute__((ext_vector_type(8))) short bf16x8;
typedef __attribute__((ext_vector_type(4))) float f32x4;

#define MFMA(a,b,c) __builtin_amdgcn_mfma_f32_16x16x32_bf16((a),(b),(c),0,0,0)

static constexpr int S  = 4096;
static constexpr int D  = 768;
static constexpr int H  = 12;
static constexpr int HD = 64;

// float -> bf16 round-nearest-even
__device__ __forceinline__ u16 f2b(float f){
  union { float f; unsigned u; } v; v.f = f;
  unsigned r = (v.u + 0x7fffu + ((v.u >> 16) & 1u)) >> 16;
  return (u16)r;
}

// pack 2 floats -> 2 bf16 (truncation) in ONE v_perm_b32
__device__ __forceinline__ unsigned pack_bf16_trunc(float a, float b){
  return __builtin_amdgcn_perm(__float_as_uint(b), __float_as_uint(a), 0x07060302u);
}

// async global->LDS 16B per lane (DMA path, no VGPR round-trip)
__device__ __forceinline__ void cp16(const u16* g, u16* l){
  __builtin_amdgcn_global_load_lds(
      (const __attribute__((address_space(1))) unsigned int*)g,
      (__attribute__((address_space(3))) unsigned int*)l, 16, 0, 0);
}

// 4-lane (quad) butterfly transpose via gfx950 permlane swaps (4 VALU instrs).
__device__ __forceinline__ bf16x8 quad_transpose(unsigned M0, unsigned M1,
                                                 unsigned M2, unsigned M3){
  auto r0 = __builtin_amdgcn_permlane32_swap(M0, M2, false, false);
  auto r1 = __builtin_amdgcn_permlane32_swap(M1, M3, false, false);
  auto s0 = __builtin_amdgcn_permlane16_swap(r0[0], r0[1], false, false);
  auto s1 = __builtin_amdgcn_permlane16_swap(r1[0], r1[1], false, false);
  union { unsigned u[4]; bf16x8 v; } r;
  r.u[0] = s0[0];
  r.u[1] = s1[0];
  r.u[2] = s0[1];
  r.u[3] = s1[1];
  return r.v;
}

// ---------------- fused cast fp32 -> bf16 for x + 4 weights ----------------
static constexpr int NX4 = (2 * S * D) / 4;   // 1572864
static constexpr int NW4 = (D * D) / 4;       // 147456
__global__ void castall(const float* __restrict__ x,  const float* __restrict__ wq,
                        const float* __restrict__ wk, const float* __restrict__ wv,
                        const float* __restrict__ wo,
                        u16* __restrict__ xb,  u16* __restrict__ wqb,
                        u16* __restrict__ wkb, u16* __restrict__ wvb,
                        u16* __restrict__ wob){
  int i = blockIdx.x * 256 + threadIdx.x;
  const float* s; u16* d; int off;
  if (i < NX4) { s = x; d = xb; off = i; }
  else {
    int j = i - NX4; int wsel = j / NW4; off = j - wsel * NW4;
    if (wsel >= 4) return;
    s = (wsel == 0) ? wq : (wsel == 1) ? wk : (wsel == 2) ? wv : wo;
    d = (wsel == 0) ? wqb : (wsel == 1) ? wkb : (wsel == 2) ? wvb : wob;
  }
  float4 v = ((const float4*)s)[off];
  uint2 o;
  o.x = (unsigned)f2b(v.x) | ((unsigned)f2b(v.y) << 16);
  o.y = (unsigned)f2b(v.z) | ((unsigned)f2b(v.w) << 16);
  ((uint2*)d)[off] = o;
}

// ---------------- QKV GEMM (m97 pattern): BK=64, global_load_lds staging, XOR-swizzled LDS.
__global__ __launch_bounds__(256, 2) void qkv_gemm(
    const u16* __restrict__ xb, const u16* __restrict__ wq, const u16* __restrict__ wk,
    const u16* __restrict__ wv, u16* __restrict__ Qb, u16* __restrict__ Kb, u16* __restrict__ Vt)
{
  __shared__ __align__(16) u16 As[128 * 64];
  __shared__ __align__(16) u16 Bs[128 * 64];
  const int t = threadIdx.x;
  const int mblk = blockIdx.x, nblk = blockIdx.y, z = blockIdx.z;
  const u16* W = (z == 0) ? wq : (z == 1) ? wk : wv;
  const int w = t >> 6, lane = t & 63, quad = lane >> 4, l16 = lane & 15;
  const int wr = w >> 1, wc = w & 1;
  const int l7 = l16 & 7;

  f32x4 acc[4][4];
  #pragma unroll
  for (int i = 0; i < 4; i++)
    #pragma unroll
    for (int j = 0; j < 4; j++) acc[i][j] = (f32x4){0.f, 0.f, 0.f, 0.f};

  int srow[4], schk[4];
  #pragma unroll
  for (int i = 0; i < 4; i++) {
    int s = i * 256 + t;
    srow[i] = s >> 3;
    schk[i] = (s & 7) ^ (srow[i] & 7);
  }
  const u16* gA = xb + (size_t)(mblk * 128) * D;
  const u16* gB = W  + (size_t)(nblk * 128) * D;

  for (int k0 = 0; k0 < D; k0 += 64) {
    __syncthreads();
    #pragma unroll
    for (int i = 0; i < 4; i++) {
      int s = i * 256 + t;
      cp16(gA + (size_t)srow[i] * D + k0 + schk[i] * 8, As + s * 8);
      cp16(gB + (size_t)srow[i] * D + k0 + schk[i] * 8, Bs + s * 8);
    }
    __syncthreads();
    #pragma unroll
    for (int j = 0; j < 2; j++) {
      bf16x8 af[4], bfr[4];
      #pragma unroll
      for (int mt = 0; mt < 4; mt++)
        af[mt]  = *(const bf16x8*)(As + (wr * 64 + mt * 16 + l16) * 64 + ((j * 4 + quad) ^ l7) * 8);
      #pragma unroll
      for (int nt = 0; nt < 4; nt++)
        bfr[nt] = *(const bf16x8*)(Bs + (wc * 64 + nt * 16 + l16) * 64 + ((j * 4 + quad) ^ l7) * 8);
      #pragma unroll
      for (int mt = 0; mt < 4; mt++)
        #pragma unroll
        for (int nt = 0; nt < 4; nt++)
          acc[mt][nt] = MFMA(af[mt], bfr[nt], acc[mt][nt]);
    }
  }

  const float qscale = 0.18033688011112042f;  // 0.125 * log2(e)
  #pragma unroll
  for (int mt = 0; mt < 4; mt++) {
    int m0 = mblk * 128 + wr * 64 + mt * 16 + quad * 4;
    #pragma unroll
    for (int nt = 0; nt < 4; nt++) {
      int n = nblk * 128 + wc * 64 + nt * 16 + l16;
      int h = n >> 6, hd = n & 63;
      if (z == 2) {
        int b = m0 >> 12, s0 = m0 & 4095;
        u16* p = Vt + (((size_t)(b * H + h) * HD + hd)) * S + s0;
        uint2 pk;
        pk.x = (unsigned)f2b(acc[mt][nt][0]) | ((unsigned)f2b(acc[mt][nt][1]) << 16);
        pk.y = (unsigned)f2b(acc[mt][nt][2]) | ((unsigned)f2b(acc[mt][nt][3]) << 16);
        *(uint2*)p = pk;
      } else {
        u16* dst = (z == 0) ? Qb : Kb;
        float sc = (z == 0) ? qscale : 1.0f;
        #pragma unroll
        for (int r = 0; r < 4; r++) {
          int m = m0 + r; int b = m >> 12, s = m & 4095;
          dst[((size_t)(b * H + h) * S + s) * HD + hd] = f2b(acc[mt][nt][r] * sc);
        }
      }
    }
  }
}

// ---------------- flash attention: dbuf K/V + counted vmcnt + raw barriers (T3/T4) ----------------
// R6 post-mortem: direct-from-L2 exposes per-fragment L2 latency (133us). R5's 45us stall is
// the vmcnt(0) drain inside __syncthreads: the 32KB/iter DMA transfer serializes behind it
// (R2's "dbuf" never overlapped for the same reason). R7: genuine 2-phase pipeline --
// stage tile i+1 (8 cp16) -> s_waitcnt vmcnt(8) (tile i done, i+1 IN FLIGHT) -> raw s_barrier
// -> compute tile i -> raw s_barrier. No vmcnt(0) in the loop; transfer hides under compute.
// All waves run all barriers (skipall waves just skip compute -- barrier parity).
// 64.5KB LDS -> 2 blocks/CU; 768 blocks longest-first (qtile=31-p/24), HW backfill balances;
// bh = p%24 keeps bh<->XCD affinity (p%8 == bh%8).
__global__ __launch_bounds__(256, 2) void attn(
    const u16* __restrict__ Qb, const u16* __restrict__ Kb,
    const u16* __restrict__ Vt, u16* __restrict__ ctx)
{
  __shared__ __align__(16) u16 Ks[2][128 * 64];   // K tile [key][hd], chunk c at c^(key&7)   : 2x16 KB
  __shared__ __align__(16) u16 Vts[2][64 * 128];  // V^T tile [hd][key], chunk c at c^(hd&15) : 2x16 KB
  __shared__ float Lbuf[2][4][16];                // lsum exchange: [wq][qt][l16]
  const int t = threadIdx.x, w = t >> 6, lane = t & 63, quad = lane >> 4, l16 = lane & 15;
  const int l7 = l16 & 7;
  const int wq = w >> 1, wk = w & 1;              // query-half, key-half of this wave

  const int p   = (int)blockIdx.x;
  const int bh    = p % 24;                       // p%8 == bh%8 -> XCD affinity
  const int qtile = 31 - p / 24;                  // longest-first dispatch order
  const int q0 = qtile * 128;
  const u16* Qh = Qb + (size_t)bh * S * HD;
  const u16* Kh = Kb + (size_t)bh * S * HD;
  const u16* Vh = Vt + (size_t)bh * S * HD;       // [64][4096]
  const int b = bh / H, h = bh % H;

  // Q fragments (B-operand): lane holds Q[q0+wq*64+qt*16+l16][ksh*32+quad*8 ..+7]
  bf16x8 qf[4][2];
  #pragma unroll
  for (int qt = 0; qt < 4; qt++)
    #pragma unroll
    for (int ksh = 0; ksh < 2; ksh++)
      qf[qt][ksh] = *(const bf16x8*)(Qh + (size_t)(q0 + wq * 64 + qt * 16 + l16) * HD + ksh * 32 + quad * 8);
  // drain Q loads so staging vmcnt arithmetic is exact from here on
  asm volatile("s_waitcnt vmcnt(0)" ::: "memory");

  // O^T acc: row=hd (co*16+quad*4+r), col=query (qt*16+l16); partial over this wave's keys
  f32x4 ao[4][4];
  #pragma unroll
  for (int qt = 0; qt < 4; qt++)
    #pragma unroll
    for (int co = 0; co < 4; co++) ao[qt][co] = (f32x4){0.f, 0.f, 0.f, 0.f};
  float lsum[4] = {0.f, 0.f, 0.f, 0.f};           // per-lane partial denominators, query qt*16+l16

  // DMA slot descriptors. K: slot s -> key s>>3, chunk (s&7)^(key&7).
  //                       V: slot s -> hd  s>>4, chunk (s&15)^(hd&15).
  int krow[4], kchk[4], vrow[4], vchk[4];
  #pragma unroll
  for (int i = 0; i < 4; i++) {
    int s = i * 256 + t;
    krow[i] = s >> 3;  kchk[i] = (s & 7)  ^ (krow[i] & 7);
    vrow[i] = s >> 4;  vchk[i] = (s & 15) ^ (vrow[i] & 15);
  }

  // stage tile kv into buffer d (8 cp16 per thread)
  auto stage = [&](int kv, int d){
    #pragma unroll
    for (int i = 0; i < 4; i++) {
      int s = i * 256 + t;
      cp16(Kh + (size_t)(kv + krow[i]) * HD + kchk[i] * 8, &Ks[d][0] + s * 8);
      cp16(Vh + (size_t)vrow[i] * S + kv + vchk[i] * 8,    &Vts[d][0] + s * 8);
    }
  };

  const int nt = q0 / 128 + 1;                    // number of 128-key tiles
  stage(0, 0);                                    // prologue

  for (int i = 0; i < nt; ++i) {
    const int cur = i & 1;
    const bool diag = (i == nt - 1);
    if (!diag) stage((i + 1) * 128, cur ^ 1);     // next tile's 8 loads
    // wait for THIS tile's 8 loads only; leave next tile's in flight across the barrier
    if (!diag) asm volatile("s_waitcnt vmcnt(8)\ns_barrier" ::: "memory");
    else       asm volatile("s_waitcnt vmcnt(0)\ns_barrier" ::: "memory");

    const bool skipall = diag && (wk > wq);       // no work, but still runs both barriers
    const bool mdiag   = diag && (wk == wq);

    if (!skipall) {
      const u16* Kc = &Ks[cur][0];
      const u16* Vc = &Vts[cur][0];
      #pragma unroll
      for (int g = 0; g < 2; g++) {               // 32-key groups within this wave's 64 keys
        unsigned pA[4][2], pB[4][2];              // [qt][ktL]: packed bf16 pairs
        #pragma unroll
        for (int ktL = 0; ktL < 2; ktL++) {
          const int kt  = g * 2 + ktL;            // 16-key tile index within 64
          const int krw = wk * 64 + kt * 16 + l16;
          bf16x8 kf0 = *(const bf16x8*)(Kc + krw * 64 + ((0 + quad) ^ l7) * 8);
          bf16x8 kf1 = *(const bf16x8*)(Kc + krw * 64 + ((4 + quad) ^ l7) * 8);
          #pragma unroll
          for (int qt = 0; qt < 4; qt++) {
            f32x4 s0 = (f32x4){0.f, 0.f, 0.f, 0.f};
            s0 = MFMA(kf0, qf[qt][0], s0);
            s0 = MFMA(kf1, qf[qt][1], s0);
            if (mdiag) {
              // key_rel = kt*16+quad*4+r, query_rel = qt*16+l16; mask key>query
              const int qoff = (qt - kt) * 16 + l16;
              #pragma unroll
              for (int r = 0; r < 4; r++)
                s0[r] = (quad * 4 + r > qoff) ? -1e30f : s0[r];
            }
            float p0 = __builtin_amdgcn_exp2f(s0[0]);
            float p1 = __builtin_amdgcn_exp2f(s0[1]);
            float p2 = __builtin_amdgcn_exp2f(s0[2]);
            float p3 = __builtin_amdgcn_exp2f(s0[3]);
            lsum[qt] += (p0 + p1) + (p2 + p3);
            pA[qt][ktL] = pack_bf16_trunc(p0, p1);
            pB[qt][ktL] = pack_bf16_trunc(p2, p3);
          }
        }
        // in-register P^T fragments for this 32-key group
        bf16x8 pf[4];
        #pragma unroll
        for (int qt = 0; qt < 4; qt++)
          pf[qt] = quad_transpose(pA[qt][0], pB[qt][0], pA[qt][1], pB[qt][1]);
        // O^T += V^T P^T
        #pragma unroll
        for (int co = 0; co < 4; co++) {
          const int vrw = co * 16 + l16;
          bf16x8 vf = *(const bf16x8*)(Vc + vrw * 128 + ((wk * 8 + g * 4 + quad) ^ (vrw & 15)) * 8);
          #pragma unroll
          for (int qt = 0; qt < 4; qt++)
            ao[qt][co] = MFMA(vf, pf[qt], ao[qt][co]);
        }
      }
    }
    asm volatile("s_barrier" ::: "memory");       // all waves done reading buf[cur]
  }

  // ---- epilogue: quad-reduce lsum, then cross-wave (wk) reduction of O and lsum ----
  #pragma unroll
  for (int qt = 0; qt < 4; qt++) {
    float v = lsum[qt];
    v += __shfl_xor(v, 16, 64);
    v += __shfl_xor(v, 32, 64);
    lsum[qt] = v;
  }

  // loop's final s_barrier ensures all compute done -> safe to reuse buffers as scratch
  float* red = wq ? (float*)&Vts[0][0] : (float*)&Ks[0][0];   // 16KB scratch per query-half pair
  if (wk == 1) {
    #pragma unroll
    for (int qt = 0; qt < 4; qt++)
      #pragma unroll
      for (int co = 0; co < 4; co++)
        *(f32x4*)(red + ((qt * 4 + co) * 64 + lane) * 4) = ao[qt][co];
    if (lane < 16) {
      #pragma unroll
      for (int qt = 0; qt < 4; qt++) Lbuf[wq][qt][lane] = lsum[qt];
    }
  }
  __syncthreads();
  if (wk == 0) {
    #pragma unroll
    for (int qt = 0; qt < 4; qt++) {
      float tot = lsum[qt] + Lbuf[wq][qt][l16];
      float inv = 1.0f / tot;
      int token = b * S + q0 + wq * 64 + qt * 16 + l16;
      #pragma unroll
      for (int co = 0; co < 4; co++) {
        f32x4 pr = *(const f32x4*)(red + ((qt * 4 + co) * 64 + lane) * 4);
        f32x4 sv = ao[qt][co] + pr;
        uint2 pk;
        pk.x = (unsigned)f2b(sv[0] * inv) | ((unsigned)f2b(sv[1] * inv) << 16);
        pk.y = (unsigned)f2b(sv[2] * inv) | ((unsigned)f2b(sv[3] * inv) << 16);
        *(uint2*)(ctx + (size_t)token * D + h * HD + co * 16 + quad * 4) = pk;
      }
    }
  }
}

// ---------------- output projection (m97 pattern): ctx[8192,768] x Wo^T + bias -> fp32 out
__global__ __launch_bounds__(256, 2) void out_gemm(
    const u16* __restrict__ ctx, const u16* __restrict__ wo,
    const float* __restrict__ bias, float* __restrict__ out)
{
  __shared__ __align__(16) u16 As[128 * 64];
  __shared__ __align__(16) u16 Bs[128 * 64];
  const int t = threadIdx.x;
  const int mblk = blockIdx.x, nblk = blockIdx.y;
  const int w = t >> 6, lane = t & 63, quad = lane >> 4, l16 = lane & 15;
  const int wr = w >> 1, wc = w & 1;
  const int l7 = l16 & 7;

  f32x4 acc[4][4];
  #pragma unroll
  for (int i = 0; i < 4; i++)
    #pragma unroll
    for (int j = 0; j < 4; j++) acc[i][j] = (f32x4){0.f, 0.f, 0.f, 0.f};

  int srow[4], schk[4];
  #pragma unroll
  for (int i = 0; i < 4; i++) {
    int s = i * 256 + t;
    srow[i] = s >> 3;
    schk[i] = (s & 7) ^ (srow[i] & 7);
  }
  const u16* gA = ctx + (size_t)(mblk * 128) * D;
  const u16* gB = wo  + (size_t)(nblk * 128) * D;

  for (int k0 = 0; k0 < D; k0 += 64) {
    __syncthreads();
    #pragma unroll
    for (int i = 0; i < 4; i++) {
      int s = i * 256 + t;
      cp16(gA + (size_t)srow[i] * D + k0 + schk[i] * 8, As + s * 8);
      cp16(gB + (size_t)srow[i] * D + k0 + schk[i] * 8, Bs + s * 8);
    }
    __syncthreads();
    #pragma unroll
    for (int j = 0; j < 2; j++) {
      bf16x8 af[4], bfr[4];
      #pragma unroll
      for (int mt = 0; mt < 4; mt++)
        af[mt]  = *(const bf16x8*)(As + (wr * 64 + mt * 16 + l16) * 64 + ((j * 4 + quad) ^ l7) * 8);
      #pragma unroll
      for (int nt = 0; nt < 4; nt++)
        bfr[nt] = *(const bf16x8*)(Bs + (wc * 64 + nt * 16 + l16) * 64 + ((j * 4 + quad) ^ l7) * 8);
      #pragma unroll
      for (int mt = 0; mt < 4; mt++)
        #pragma unroll
        for (int nt = 0; nt < 4; nt++)
          acc[mt][nt] = MFMA(af[mt], bfr[nt], acc[mt][nt]);
    }
  }

  #pragma unroll
  for (int mt = 0; mt < 4; mt++) {
    int m0 = mblk * 128 + wr * 64 + mt * 16 + quad * 4;
    #pragma unroll
    for (int nt = 0; nt < 4; nt++) {
      int n = nblk * 128 + wc * 64 + nt * 16 + l16;
      float bv = bias[n];
      #pragma unroll
      for (int r = 0; r < 4; r++)
        out[(size_t)(m0 + r) * D + n] = acc[mt][nt][r] + bv;
    }
  }
}

// ---------------- host launch ----------------
extern "C" void kernel_launch(void* const* d_in, const int* in_sizes, int n_in,
                              void* d_out, int out_size, void* d_ws, size_t ws_size,
                              hipStream_t stream) {
  const float* x    = (const float*)d_in[0];
  const float* wq   = (const float*)d_in[1];
  const float* wk   = (const float*)d_in[2];
  const float* wv   = (const float*)d_in[3];
  const float* wo   = (const float*)d_in[4];
  const float* bo   = (const float*)d_in[5];
  float* out = (float*)d_out;

  u16* ws = (u16*)d_ws;
  const size_t NX = (size_t)2 * S * D;      // 6291456
  const size_t NW = (size_t)D * D;          // 589824
  u16* xb  = ws;                // [8192][768]; reused as ctx after qkv_gemm consumes it
  u16* wqb = ws + NX;
  u16* wkb = wqb + NW;
  u16* wvb = wkb + NW;
  u16* wob = wvb + NW;
  u16* Qb  = wob + NW;          // [2][12][4096][64] bf16 (pre-scaled by 0.125*log2e)
  u16* Kb  = Qb + NX;           // bf16
  u16* Vt  = Kb + NX;           // [2][12][64][4096] bf16
  u16* ctx = xb;

  const int total4 = NX4 + 4 * NW4;
  castall<<<(total4 + 255) / 256, 256, 0, stream>>>(x, wq, wk, wv, wo, xb, wqb, wkb, wvb, wob);

  qkv_gemm<<<dim3(64, 6, 3), 256, 0, stream>>>(xb, wqb, wkb, wvb, Qb, Kb, Vt);
  attn<<<dim3(768), 256, 0, stream>>>(Qb, Kb, Vt, ctx);
  out_gemm<<<dim3(64, 6), 256, 0, stream>>>(ctx, wob, bo, out);
}

// Round 8
// 214.573 us; speedup vs baseline: 1.2263x; 1.0040x over previous
//
#include <hip/hip_runtime.h>
#include <stdint.h>

typedef unsigned short u16;
typedef __attribute__((ext_vector_type(8))) short bf16x8;
typedef __attribute__((ext_vector_type(4))) float f32x4;

#define MFMA(a,b,c) __builtin_amdgcn_mfma_f32_16x16x32_bf16((a),(b),(c),0,0,0)

static constexpr int S  = 4096;
static constexpr int D  = 768;
static constexpr int H  = 12;
static constexpr int HD = 64;

// float -> bf16 round-nearest-even
__device__ __forceinline__ u16 f2b(float f){
  union { float f; unsigned u; } v; v.f = f;
  unsigned r = (v.u + 0x7fffu + ((v.u >> 16) & 1u)) >> 16;
  return (u16)r;
}

// pack 2 floats -> 2 bf16 (truncation) in ONE v_perm_b32
__device__ __forceinline__ unsigned pack_bf16_trunc(float a, float b){
  return __builtin_amdgcn_perm(__float_as_uint(b), __float_as_uint(a), 0x07060302u);
}

// async global->LDS 16B per lane (DMA path, no VGPR round-trip)
__device__ __forceinline__ void cp16(const u16* g, u16* l){
  __builtin_amdgcn_global_load_lds(
      (const __attribute__((address_space(1))) unsigned int*)g,
      (__attribute__((address_space(3))) unsigned int*)l, 16, 0, 0);
}

// 4-lane (quad) butterfly transpose via gfx950 permlane swaps (4 VALU instrs).
__device__ __forceinline__ bf16x8 quad_transpose(unsigned M0, unsigned M1,
                                                 unsigned M2, unsigned M3){
  auto r0 = __builtin_amdgcn_permlane32_swap(M0, M2, false, false);
  auto r1 = __builtin_amdgcn_permlane32_swap(M1, M3, false, false);
  auto s0 = __builtin_amdgcn_permlane16_swap(r0[0], r0[1], false, false);
  auto s1 = __builtin_amdgcn_permlane16_swap(r1[0], r1[1], false, false);
  union { unsigned u[4]; bf16x8 v; } r;
  r.u[0] = s0[0];
  r.u[1] = s1[0];
  r.u[2] = s0[1];
  r.u[3] = s1[1];
  return r.v;
}

// ---------------- fused cast fp32 -> bf16 for x + 4 weights ----------------
static constexpr int NX4 = (2 * S * D) / 4;   // 1572864
static constexpr int NW4 = (D * D) / 4;       // 147456
__global__ void castall(const float* __restrict__ x,  const float* __restrict__ wq,
                        const float* __restrict__ wk, const float* __restrict__ wv,
                        const float* __restrict__ wo,
                        u16* __restrict__ xb,  u16* __restrict__ wqb,
                        u16* __restrict__ wkb, u16* __restrict__ wvb,
                        u16* __restrict__ wob){
  int i = blockIdx.x * 256 + threadIdx.x;
  const float* s; u16* d; int off;
  if (i < NX4) { s = x; d = xb; off = i; }
  else {
    int j = i - NX4; int wsel = j / NW4; off = j - wsel * NW4;
    if (wsel >= 4) return;
    s = (wsel == 0) ? wq : (wsel == 1) ? wk : (wsel == 2) ? wv : wo;
    d = (wsel == 0) ? wqb : (wsel == 1) ? wkb : (wsel == 2) ? wvb : wob;
  }
  float4 v = ((const float4*)s)[off];
  uint2 o;
  o.x = (unsigned)f2b(v.x) | ((unsigned)f2b(v.y) << 16);
  o.y = (unsigned)f2b(v.z) | ((unsigned)f2b(v.w) << 16);
  ((uint2*)d)[off] = o;
}

// ---------------- QKV GEMM (m97 pattern): BK=64, global_load_lds staging, XOR-swizzled LDS.
__global__ __launch_bounds__(256, 2) void qkv_gemm(
    const u16* __restrict__ xb, const u16* __restrict__ wq, const u16* __restrict__ wk,
    const u16* __restrict__ wv, u16* __restrict__ Qb, u16* __restrict__ Kb, u16* __restrict__ Vt)
{
  __shared__ __align__(16) u16 As[128 * 64];
  __shared__ __align__(16) u16 Bs[128 * 64];
  const int t = threadIdx.x;
  const int mblk = blockIdx.x, nblk = blockIdx.y, z = blockIdx.z;
  const u16* W = (z == 0) ? wq : (z == 1) ? wk : wv;
  const int w = t >> 6, lane = t & 63, quad = lane >> 4, l16 = lane & 15;
  const int wr = w >> 1, wc = w & 1;
  const int l7 = l16 & 7;

  f32x4 acc[4][4];
  #pragma unroll
  for (int i = 0; i < 4; i++)
    #pragma unroll
    for (int j = 0; j < 4; j++) acc[i][j] = (f32x4){0.f, 0.f, 0.f, 0.f};

  int srow[4], schk[4];
  #pragma unroll
  for (int i = 0; i < 4; i++) {
    int s = i * 256 + t;
    srow[i] = s >> 3;
    schk[i] = (s & 7) ^ (srow[i] & 7);
  }
  const u16* gA = xb + (size_t)(mblk * 128) * D;
  const u16* gB = W  + (size_t)(nblk * 128) * D;

  for (int k0 = 0; k0 < D; k0 += 64) {
    __syncthreads();
    #pragma unroll
    for (int i = 0; i < 4; i++) {
      int s = i * 256 + t;
      cp16(gA + (size_t)srow[i] * D + k0 + schk[i] * 8, As + s * 8);
      cp16(gB + (size_t)srow[i] * D + k0 + schk[i] * 8, Bs + s * 8);
    }
    __syncthreads();
    #pragma unroll
    for (int j = 0; j < 2; j++) {
      bf16x8 af[4], bfr[4];
      #pragma unroll
      for (int mt = 0; mt < 4; mt++)
        af[mt]  = *(const bf16x8*)(As + (wr * 64 + mt * 16 + l16) * 64 + ((j * 4 + quad) ^ l7) * 8);
      #pragma unroll
      for (int nt = 0; nt < 4; nt++)
        bfr[nt] = *(const bf16x8*)(Bs + (wc * 64 + nt * 16 + l16) * 64 + ((j * 4 + quad) ^ l7) * 8);
      #pragma unroll
      for (int mt = 0; mt < 4; mt++)
        #pragma unroll
        for (int nt = 0; nt < 4; nt++)
          acc[mt][nt] = MFMA(af[mt], bfr[nt], acc[mt][nt]);
    }
  }

  const float qscale = 0.18033688011112042f;  // 0.125 * log2(e)
  #pragma unroll
  for (int mt = 0; mt < 4; mt++) {
    int m0 = mblk * 128 + wr * 64 + mt * 16 + quad * 4;
    #pragma unroll
    for (int nt = 0; nt < 4; nt++) {
      int n = nblk * 128 + wc * 64 + nt * 16 + l16;
      int h = n >> 6, hd = n & 63;
      if (z == 2) {
        int b = m0 >> 12, s0 = m0 & 4095;
        u16* p = Vt + (((size_t)(b * H + h) * HD + hd)) * S + s0;
        uint2 pk;
        pk.x = (unsigned)f2b(acc[mt][nt][0]) | ((unsigned)f2b(acc[mt][nt][1]) << 16);
        pk.y = (unsigned)f2b(acc[mt][nt][2]) | ((unsigned)f2b(acc[mt][nt][3]) << 16);
        *(uint2*)p = pk;
      } else {
        u16* dst = (z == 0) ? Qb : Kb;
        float sc = (z == 0) ? qscale : 1.0f;
        #pragma unroll
        for (int r = 0; r < 4; r++) {
          int m = m0 + r; int b = m >> 12, s = m & 4095;
          dst[((size_t)(b * H + h) * S + s) * HD + hd] = f2b(acc[mt][nt][r] * sc);
        }
      }
    }
  }
}

// ---------------- flash attention: 64-query blocks for sustained occupancy ----------------
// R0-R7 pattern: only concurrency ever moved wall time (2/CU structures 90-94us, 3/CU 82-93us;
// all per-iter optimizations absorbed by stall). avg occupancy pinned ~17% because the GRID
// (768) is the residency limiter: 3 blocks/CU at t=0, no backfill queue, triangular decay.
// R8: split to 64-QUERY blocks. Same verified compute body, each wave 32q x 64k (qt range 2).
// Grid 1536 at unchanged 33KB LDS -> 4 blocks/CU resident + 512-block backfill queue ->
// sustained ~16 waves/CU. Staging traffic doubles (811MB L2->LDS, ~13TB/s < 34TB/s ceiling).
// Longest-first (qtile64 = 63 - p/24) => greedy-LPT backfill; bh = p%24 keeps XCD affinity.
__global__ __launch_bounds__(256, 2) void attn(
    const u16* __restrict__ Qb, const u16* __restrict__ Kb,
    const u16* __restrict__ Vt, u16* __restrict__ ctx)
{
  __shared__ __align__(16) u16 Ks[128 * 64];    // K tile [key][hd], chunk c at c^(key&7)   : 16 KB
  __shared__ __align__(16) u16 Vts[64 * 128];   // V^T tile [hd][key], chunk c at c^(hd&15) : 16 KB
  __shared__ float Lbuf[2][2][16];              // lsum exchange: [wq][qt][l16]
  const int t = threadIdx.x, w = t >> 6, lane = t & 63, quad = lane >> 4, l16 = lane & 15;
  const int l7 = l16 & 7;
  const int wq = w >> 1, wk = w & 1;            // query-half (32q), key-half (64k) of this wave

  const int p       = (int)blockIdx.x;
  const int bh      = p % 24;                   // p%8 == bh%8 -> XCD affinity
  const int qtile64 = 63 - p / 24;              // longest-first dispatch order
  const int q0   = qtile64 * 64;
  const int nt   = qtile64 / 2 + 1;             // number of 128-key tiles
  const int doff = qtile64 & 1;                 // which wk holds the diagonal on the last tile

  const u16* Qh = Qb + (size_t)bh * S * HD;
  const u16* Kh = Kb + (size_t)bh * S * HD;
  const u16* Vh = Vt + (size_t)bh * S * HD;     // [64][4096]
  const int b = bh / H, h = bh % H;

  // Q fragments (B-operand): lane holds Q[q0+wq*32+qt*16+l16][ksh*32+quad*8 ..+7]
  bf16x8 qf[2][2];
  #pragma unroll
  for (int qt = 0; qt < 2; qt++)
    #pragma unroll
    for (int ksh = 0; ksh < 2; ksh++)
      qf[qt][ksh] = *(const bf16x8*)(Qh + (size_t)(q0 + wq * 32 + qt * 16 + l16) * HD + ksh * 32 + quad * 8);

  // O^T acc: row=hd (co*16+quad*4+r), col=query (qt*16+l16); partial over this wave's keys
  f32x4 ao[2][4];
  #pragma unroll
  for (int qt = 0; qt < 2; qt++)
    #pragma unroll
    for (int co = 0; co < 4; co++) ao[qt][co] = (f32x4){0.f, 0.f, 0.f, 0.f};
  float lsum[2] = {0.f, 0.f};                   // per-lane partial denominators, query qt*16+l16

  // DMA slot descriptors. K: slot s -> key s>>3, chunk (s&7)^(key&7).
  //                       V: slot s -> hd  s>>4, chunk (s&15)^(hd&15).
  int krow[4], kchk[4], vrow[4], vchk[4];
  #pragma unroll
  for (int i = 0; i < 4; i++) {
    int s = i * 256 + t;
    krow[i] = s >> 3;  kchk[i] = (s & 7)  ^ (krow[i] & 7);
    vrow[i] = s >> 4;  vchk[i] = (s & 15) ^ (vrow[i] & 15);
  }

  for (int it = 0; it < nt; ++it) {
    const int kv0 = it * 128;
    const bool diag    = (it == nt - 1);
    const bool skipall = diag && (wk == 1) && (doff == 0);  // keys entirely above queries
    const bool mdiag   = diag && (wk == doff);              // element-mask region
    // (diag && wk==0 && doff==1: fully below diagonal -> unmasked compute)

    __syncthreads();   // prior iter's LDS reads complete
    #pragma unroll
    for (int i = 0; i < 4; i++) {
      int s = i * 256 + t;
      cp16(Kh + (size_t)(kv0 + krow[i]) * HD + kchk[i] * 8, Ks + s * 8);
      cp16(Vh + (size_t)vrow[i] * S + kv0 + vchk[i] * 8,    Vts + s * 8);
    }
    __syncthreads();   // DMA arrived (vmcnt drained at barrier)

    if (!skipall) {
      #pragma unroll
      for (int g = 0; g < 2; g++) {             // 32-key groups within this wave's 64 keys
        unsigned pA[2][2], pB[2][2];            // [qt][ktL]: packed bf16 pairs
        #pragma unroll
        for (int ktL = 0; ktL < 2; ktL++) {
          const int kt  = g * 2 + ktL;          // 16-key tile index within 64
          const int krw = wk * 64 + kt * 16 + l16;
          bf16x8 kf0 = *(const bf16x8*)(Ks + krw * 64 + ((0 + quad) ^ l7) * 8);
          bf16x8 kf1 = *(const bf16x8*)(Ks + krw * 64 + ((4 + quad) ^ l7) * 8);
          #pragma unroll
          for (int qt = 0; qt < 2; qt++) {
            f32x4 s0 = (f32x4){0.f, 0.f, 0.f, 0.f};
            s0 = MFMA(kf0, qf[qt][0], s0);
            s0 = MFMA(kf1, qf[qt][1], s0);
            if (mdiag) {
              // key_rel = kt*16+quad*4+r, query_rel = wq*32+qt*16+l16; mask key>query
              const int qoff = wq * 32 + (qt - kt) * 16 + l16;
              #pragma unroll
              for (int r = 0; r < 4; r++)
                s0[r] = (quad * 4 + r > qoff) ? -1e30f : s0[r];
            }
            float p0 = __builtin_amdgcn_exp2f(s0[0]);
            float p1 = __builtin_amdgcn_exp2f(s0[1]);
            float p2 = __builtin_amdgcn_exp2f(s0[2]);
            float p3 = __builtin_amdgcn_exp2f(s0[3]);
            lsum[qt] += (p0 + p1) + (p2 + p3);
            pA[qt][ktL] = pack_bf16_trunc(p0, p1);
            pB[qt][ktL] = pack_bf16_trunc(p2, p3);
          }
        }
        // in-register P^T fragments for this 32-key group
        bf16x8 pf[2];
        #pragma unroll
        for (int qt = 0; qt < 2; qt++)
          pf[qt] = quad_transpose(pA[qt][0], pB[qt][0], pA[qt][1], pB[qt][1]);
        // O^T += V^T P^T
        #pragma unroll
        for (int co = 0; co < 4; co++) {
          const int vrw = co * 16 + l16;
          bf16x8 vf = *(const bf16x8*)(Vts + vrw * 128 + ((wk * 8 + g * 4 + quad) ^ (vrw & 15)) * 8);
          #pragma unroll
          for (int qt = 0; qt < 2; qt++)
            ao[qt][co] = MFMA(vf, pf[qt], ao[qt][co]);
        }
      }
    }
  }

  // ---- epilogue: quad-reduce lsum, then cross-wave (wk) reduction of O and lsum ----
  #pragma unroll
  for (int qt = 0; qt < 2; qt++) {
    float v = lsum[qt];
    v += __shfl_xor(v, 16, 64);
    v += __shfl_xor(v, 32, 64);
    lsum[qt] = v;
  }

  __syncthreads();                              // all loop-phase LDS reads done
  float* red = wq ? (float*)Vts : (float*)Ks;   // 16KB scratch per query-half pair (8KB used)
  if (wk == 1) {
    #pragma unroll
    for (int qt = 0; qt < 2; qt++)
      #pragma unroll
      for (int co = 0; co < 4; co++)
        *(f32x4*)(red + ((qt * 4 + co) * 64 + lane) * 4) = ao[qt][co];
    if (lane < 16) {
      #pragma unroll
      for (int qt = 0; qt < 2; qt++) Lbuf[wq][qt][lane] = lsum[qt];
    }
  }
  __syncthreads();
  if (wk == 0) {
    #pragma unroll
    for (int qt = 0; qt < 2; qt++) {
      float tot = lsum[qt] + Lbuf[wq][qt][l16];
      float inv = 1.0f / tot;
      int token = b * S + q0 + wq * 32 + qt * 16 + l16;
      #pragma unroll
      for (int co = 0; co < 4; co++) {
        f32x4 pr = *(const f32x4*)(red + ((qt * 4 + co) * 64 + lane) * 4);
        f32x4 sv = ao[qt][co] + pr;
        uint2 pk;
        pk.x = (unsigned)f2b(sv[0] * inv) | ((unsigned)f2b(sv[1] * inv) << 16);
        pk.y = (unsigned)f2b(sv[2] * inv) | ((unsigned)f2b(sv[3] * inv) << 16);
        *(uint2*)(ctx + (size_t)token * D + h * HD + co * 16 + quad * 4) = pk;
      }
    }
  }
}

// ---------------- output projection (m97 pattern): ctx[8192,768] x Wo^T + bias -> fp32 out
__global__ __launch_bounds__(256, 2) void out_gemm(
    const u16* __restrict__ ctx, const u16* __restrict__ wo,
    const float* __restrict__ bias, float* __restrict__ out)
{
  __shared__ __align__(16) u16 As[128 * 64];
  __shared__ __align__(16) u16 Bs[128 * 64];
  const int t = threadIdx.x;
  const int mblk = blockIdx.x, nblk = blockIdx.y;
  const int w = t >> 6, lane = t & 63, quad = lane >> 4, l16 = lane & 15;
  const int wr = w >> 1, wc = w & 1;
  const int l7 = l16 & 7;

  f32x4 acc[4][4];
  #pragma unroll
  for (int i = 0; i < 4; i++)
    #pragma unroll
    for (int j = 0; j < 4; j++) acc[i][j] = (f32x4){0.f, 0.f, 0.f, 0.f};

  int srow[4], schk[4];
  #pragma unroll
  for (int i = 0; i < 4; i++) {
    int s = i * 256 + t;
    srow[i] = s >> 3;
    schk[i] = (s & 7) ^ (srow[i] & 7);
  }
  const u16* gA = ctx + (size_t)(mblk * 128) * D;
  const u16* gB = wo  + (size_t)(nblk * 128) * D;

  for (int k0 = 0; k0 < D; k0 += 64) {
    __syncthreads();
    #pragma unroll
    for (int i = 0; i < 4; i++) {
      int s = i * 256 + t;
      cp16(gA + (size_t)srow[i] * D + k0 + schk[i] * 8, As + s * 8);
      cp16(gB + (size_t)srow[i] * D + k0 + schk[i] * 8, Bs + s * 8);
    }
    __syncthreads();
    #pragma unroll
    for (int j = 0; j < 2; j++) {
      bf16x8 af[4], bfr[4];
      #pragma unroll
      for (int mt = 0; mt < 4; mt++)
        af[mt]  = *(const bf16x8*)(As + (wr * 64 + mt * 16 + l16) * 64 + ((j * 4 + quad) ^ l7) * 8);
      #pragma unroll
      for (int nt = 0; nt < 4; nt++)
        bfr[nt] = *(const bf16x8*)(Bs + (wc * 64 + nt * 16 + l16) * 64 + ((j * 4 + quad) ^ l7) * 8);
      #pragma unroll
      for (int mt = 0; mt < 4; mt++)
        #pragma unroll
        for (int nt = 0; nt < 4; nt++)
          acc[mt][nt] = MFMA(af[mt], bfr[nt], acc[mt][nt]);
    }
  }

  #pragma unroll
  for (int mt = 0; mt < 4; mt++) {
    int m0 = mblk * 128 + wr * 64 + mt * 16 + quad * 4;
    #pragma unroll
    for (int nt = 0; nt < 4; nt++) {
      int n = nblk * 128 + wc * 64 + nt * 16 + l16;
      float bv = bias[n];
      #pragma unroll
      for (int r = 0; r < 4; r++)
        out[(size_t)(m0 + r) * D + n] = acc[mt][nt][r] + bv;
    }
  }
}

// ---------------- host launch ----------------
extern "C" void kernel_launch(void* const* d_in, const int* in_sizes, int n_in,
                              void* d_out, int out_size, void* d_ws, size_t ws_size,
                              hipStream_t stream) {
  const float* x    = (const float*)d_in[0];
  const float* wq   = (const float*)d_in[1];
  const float* wk   = (const float*)d_in[2];
  const float* wv   = (const float*)d_in[3];
  const float* wo   = (const float*)d_in[4];
  const float* bo   = (const float*)d_in[5];
  float* out = (float*)d_out;

  u16* ws = (u16*)d_ws;
  const size_t NX = (size_t)2 * S * D;      // 6291456
  const size_t NW = (size_t)D * D;          // 589824
  u16* xb  = ws;                // [8192][768]; reused as ctx after qkv_gemm consumes it
  u16* wqb = ws + NX;
  u16* wkb = wqb + NW;
  u16* wvb = wkb + NW;
  u16* wob = wvb + NW;
  u16* Qb  = wob + NW;          // [2][12][4096][64] bf16 (pre-scaled by 0.125*log2e)
  u16* Kb  = Qb + NX;           // bf16
  u16* Vt  = Kb + NX;           // [2][12][64][4096] bf16
  u16* ctx = xb;

  const int total4 = NX4 + 4 * NW4;
  castall<<<(total4 + 255) / 256, 256, 0, stream>>>(x, wq, wk, wv, wo, xb, wqb, wkb, wvb, wob);

  qkv_gemm<<<dim3(64, 6, 3), 256, 0, stream>>>(xb, wqb, wkb, wvb, Qb, Kb, Vt);
  attn<<<dim3(1536), 256, 0, stream>>>(Qb, Kb, Vt, ctx);
  out_gemm<<<dim3(64, 6), 256, 0, stream>>>(ctx, wob, bo, out);
}

// Round 9
// 211.834 us; speedup vs baseline: 1.2422x; 1.0129x over previous
//
#include <hip/hip_runtime.h>
#include <stdint.h>

typedef unsigned short u16;
typedef __attribute__((ext_vector_type(8))) short bf16x8;
typedef __attribute__((ext_vector_type(4))) float f32x4;

#define MFMA(a,b,c) __builtin_amdgcn_mfma_f32_16x16x32_bf16((a),(b),(c),0,0,0)

static constexpr int S  = 4096;
static constexpr int D  = 768;
static constexpr int H  = 12;
static constexpr int HD = 64;

// float -> bf16 round-nearest-even
__device__ __forceinline__ u16 f2b(float f){
  union { float f; unsigned u; } v; v.f = f;
  unsigned r = (v.u + 0x7fffu + ((v.u >> 16) & 1u)) >> 16;
  return (u16)r;
}

// pack 2 floats -> 2 bf16 (truncation) in ONE v_perm_b32
__device__ __forceinline__ unsigned pack_bf16_trunc(float a, float b){
  return __builtin_amdgcn_perm(__float_as_uint(b), __float_as_uint(a), 0x07060302u);
}

// async global->LDS 16B per lane (DMA path, no VGPR round-trip)
__device__ __forceinline__ void cp16(const u16* g, u16* l){
  __builtin_amdgcn_global_load_lds(
      (const __attribute__((address_space(1))) unsigned int*)g,
      (__attribute__((address_space(3))) unsigned int*)l, 16, 0, 0);
}

// 4-lane (quad) butterfly transpose via gfx950 permlane swaps (4 VALU instrs).
__device__ __forceinline__ bf16x8 quad_transpose(unsigned M0, unsigned M1,
                                                 unsigned M2, unsigned M3){
  auto r0 = __builtin_amdgcn_permlane32_swap(M0, M2, false, false);
  auto r1 = __builtin_amdgcn_permlane32_swap(M1, M3, false, false);
  auto s0 = __builtin_amdgcn_permlane16_swap(r0[0], r0[1], false, false);
  auto s1 = __builtin_amdgcn_permlane16_swap(r1[0], r1[1], false, false);
  union { unsigned u[4]; bf16x8 v; } r;
  r.u[0] = s0[0];
  r.u[1] = s1[0];
  r.u[2] = s0[1];
  r.u[3] = s1[1];
  return r.v;
}

// ---------------- fused cast fp32 -> bf16 for x + 4 weights ----------------
static constexpr int NX4 = (2 * S * D) / 4;   // 1572864
static constexpr int NW4 = (D * D) / 4;       // 147456
__global__ void castall(const float* __restrict__ x,  const float* __restrict__ wq,
                        const float* __restrict__ wk, const float* __restrict__ wv,
                        const float* __restrict__ wo,
                        u16* __restrict__ xb,  u16* __restrict__ wqb,
                        u16* __restrict__ wkb, u16* __restrict__ wvb,
                        u16* __restrict__ wob){
  int i = blockIdx.x * 256 + threadIdx.x;
  const float* s; u16* d; int off;
  if (i < NX4) { s = x; d = xb; off = i; }
  else {
    int j = i - NX4; int wsel = j / NW4; off = j - wsel * NW4;
    if (wsel >= 4) return;
    s = (wsel == 0) ? wq : (wsel == 1) ? wk : (wsel == 2) ? wv : wo;
    d = (wsel == 0) ? wqb : (wsel == 1) ? wkb : (wsel == 2) ? wvb : wob;
  }
  float4 v = ((const float4*)s)[off];
  uint2 o;
  o.x = (unsigned)f2b(v.x) | ((unsigned)f2b(v.y) << 16);
  o.y = (unsigned)f2b(v.z) | ((unsigned)f2b(v.w) << 16);
  ((uint2*)d)[off] = o;
}

// ---------------- QKV GEMM (m97 pattern): BK=64, global_load_lds staging, XOR-swizzled LDS.
__global__ __launch_bounds__(256, 2) void qkv_gemm(
    const u16* __restrict__ xb, const u16* __restrict__ wq, const u16* __restrict__ wk,
    const u16* __restrict__ wv, u16* __restrict__ Qb, u16* __restrict__ Kb, u16* __restrict__ Vt)
{
  __shared__ __align__(16) u16 As[128 * 64];
  __shared__ __align__(16) u16 Bs[128 * 64];
  const int t = threadIdx.x;
  const int mblk = blockIdx.x, nblk = blockIdx.y, z = blockIdx.z;
  const u16* W = (z == 0) ? wq : (z == 1) ? wk : wv;
  const int w = t >> 6, lane = t & 63, quad = lane >> 4, l16 = lane & 15;
  const int wr = w >> 1, wc = w & 1;
  const int l7 = l16 & 7;

  f32x4 acc[4][4];
  #pragma unroll
  for (int i = 0; i < 4; i++)
    #pragma unroll
    for (int j = 0; j < 4; j++) acc[i][j] = (f32x4){0.f, 0.f, 0.f, 0.f};

  int srow[4], schk[4];
  #pragma unroll
  for (int i = 0; i < 4; i++) {
    int s = i * 256 + t;
    srow[i] = s >> 3;
    schk[i] = (s & 7) ^ (srow[i] & 7);
  }
  const u16* gA = xb + (size_t)(mblk * 128) * D;
  const u16* gB = W  + (size_t)(nblk * 128) * D;

  for (int k0 = 0; k0 < D; k0 += 64) {
    __syncthreads();
    #pragma unroll
    for (int i = 0; i < 4; i++) {
      int s = i * 256 + t;
      cp16(gA + (size_t)srow[i] * D + k0 + schk[i] * 8, As + s * 8);
      cp16(gB + (size_t)srow[i] * D + k0 + schk[i] * 8, Bs + s * 8);
    }
    __syncthreads();
    #pragma unroll
    for (int j = 0; j < 2; j++) {
      bf16x8 af[4], bfr[4];
      #pragma unroll
      for (int mt = 0; mt < 4; mt++)
        af[mt]  = *(const bf16x8*)(As + (wr * 64 + mt * 16 + l16) * 64 + ((j * 4 + quad) ^ l7) * 8);
      #pragma unroll
      for (int nt = 0; nt < 4; nt++)
        bfr[nt] = *(const bf16x8*)(Bs + (wc * 64 + nt * 16 + l16) * 64 + ((j * 4 + quad) ^ l7) * 8);
      #pragma unroll
      for (int mt = 0; mt < 4; mt++)
        #pragma unroll
        for (int nt = 0; nt < 4; nt++)
          acc[mt][nt] = MFMA(af[mt], bfr[nt], acc[mt][nt]);
    }
  }

  const float qscale = 0.18033688011112042f;  // 0.125 * log2(e)
  #pragma unroll
  for (int mt = 0; mt < 4; mt++) {
    int m0 = mblk * 128 + wr * 64 + mt * 16 + quad * 4;
    #pragma unroll
    for (int nt = 0; nt < 4; nt++) {
      int n = nblk * 128 + wc * 64 + nt * 16 + l16;
      int h = n >> 6, hd = n & 63;
      if (z == 2) {
        int b = m0 >> 12, s0 = m0 & 4095;
        u16* p = Vt + (((size_t)(b * H + h) * HD + hd)) * S + s0;
        uint2 pk;
        pk.x = (unsigned)f2b(acc[mt][nt][0]) | ((unsigned)f2b(acc[mt][nt][1]) << 16);
        pk.y = (unsigned)f2b(acc[mt][nt][2]) | ((unsigned)f2b(acc[mt][nt][3]) << 16);
        *(uint2*)p = pk;
      } else {
        u16* dst = (z == 0) ? Qb : Kb;
        float sc = (z == 0) ? qscale : 1.0f;
        #pragma unroll
        for (int r = 0; r < 4; r++) {
          int m = m0 + r; int b = m >> 12, s = m & 4095;
          dst[((size_t)(b * H + h) * S + s) * HD + hd] = f2b(acc[mt][nt][r] * sc);
        }
      }
    }
  }
}

// ---------------- flash attention: 64-key dbuf tiles + counted vmcnt at 4 blocks/CU ----------------
// R8 post-mortem: occupancy 17->35% but dur flat at 83.5us; remaining 42% stall is the per-iter
// vmcnt(0)-in-__syncthreads drain (~600-900cyc x ~100 block-iters/CU) that co-resident blocks
// can't fully cover. R7's counted-vmcnt pipeline fixed exactly this but cost residency (66KB).
// R9: shrink tile to 64 keys -> dbuf fits 32KB: Ks[2][64x64] + Vts[2][64x64]. Per iter: stage
// NEXT tile (4 cp16) -> s_waitcnt vmcnt(4) (current tile done, next stays in flight) ->
// s_barrier -> compute -> s_barrier. No vmcnt(0) in loop; drain hides under compute at
// UNCHANGED 4 blocks/CU. Wave split: 2x2 of 32q x 32k. + T5 setprio around MFMA clusters
// (m191 regime: independent blocks at drifted phases).
// grid 1536: bh = p%24 (XCD affinity), qtile64 = 63-p/24 (longest-first backfill).
__global__ __launch_bounds__(256, 2) void attn(
    const u16* __restrict__ Qb, const u16* __restrict__ Kb,
    const u16* __restrict__ Vt, u16* __restrict__ ctx)
{
  __shared__ __align__(16) u16 Ks[2][64 * 64];   // K tile [key][hd], chunk c at c^(key&7)  : 2x8 KB
  __shared__ __align__(16) u16 Vts[2][64 * 64];  // V^T tile [hd][key], chunk c at c^(hd&7) : 2x8 KB
  __shared__ float Lbuf[2][2][16];               // lsum exchange: [wq][qt][l16]
  const int t = threadIdx.x, w = t >> 6, lane = t & 63, quad = lane >> 4, l16 = lane & 15;
  const int l7 = l16 & 7;
  const int wq = w >> 1, wk = w & 1;             // query-half (32q), key-half (32k of 64) of wave

  const int p       = (int)blockIdx.x;
  const int bh      = p % 24;                    // p%8 == bh%8 -> XCD affinity
  const int qtile64 = 63 - p / 24;               // longest-first dispatch order
  const int q0 = qtile64 * 64;
  const int nt = qtile64 + 1;                    // number of 64-key tiles

  const u16* Qh = Qb + (size_t)bh * S * HD;
  const u16* Kh = Kb + (size_t)bh * S * HD;
  const u16* Vh = Vt + (size_t)bh * S * HD;      // [64][4096]
  const int b = bh / H, h = bh % H;

  // Q fragments (B-operand): lane holds Q[q0+wq*32+qt*16+l16][ksh*32+quad*8 ..+7]
  bf16x8 qf[2][2];
  #pragma unroll
  for (int qt = 0; qt < 2; qt++)
    #pragma unroll
    for (int ksh = 0; ksh < 2; ksh++)
      qf[qt][ksh] = *(const bf16x8*)(Qh + (size_t)(q0 + wq * 32 + qt * 16 + l16) * HD + ksh * 32 + quad * 8);
  // drain Q loads so staging vmcnt arithmetic is exact from here on
  asm volatile("s_waitcnt vmcnt(0)" ::: "memory");

  // O^T acc: row=hd (co*16+quad*4+r), col=query (qt*16+l16); partial over this wave's keys
  f32x4 ao[2][4];
  #pragma unroll
  for (int qt = 0; qt < 2; qt++)
    #pragma unroll
    for (int co = 0; co < 4; co++) ao[qt][co] = (f32x4){0.f, 0.f, 0.f, 0.f};
  float lsum[2] = {0.f, 0.f};

  // DMA slot descriptors: 512 slots each for K and V (2/thread each).
  // slot s -> row s>>3 (key for K, hd for V), chunk (s&7)^(row&7); rows r0, r0+32 share chunk.
  const int r0 = t >> 3;
  const int c0 = (t & 7) ^ (r0 & 7);

  // stage 64-key tile starting at kv into buffer d (4 cp16 per thread)
  auto stage = [&](int kv, int d){
    cp16(Kh + (size_t)(kv + r0)      * HD + c0 * 8, &Ks[d][0] + t * 8);
    cp16(Kh + (size_t)(kv + r0 + 32) * HD + c0 * 8, &Ks[d][0] + (t + 256) * 8);
    cp16(Vh + (size_t)r0 * S        + kv + c0 * 8, &Vts[d][0] + t * 8);
    cp16(Vh + (size_t)(r0 + 32) * S + kv + c0 * 8, &Vts[d][0] + (t + 256) * 8);
  };

  stage(0, 0);                                   // prologue

  for (int it = 0; it < nt; ++it) {
    const int cur = it & 1;
    const bool diag = (it == nt - 1);
    if (!diag) stage((it + 1) * 64, cur ^ 1);    // next tile's 4 loads
    // wait for THIS tile's 4 loads only; leave next tile's in flight across the barrier
    if (!diag) asm volatile("s_waitcnt vmcnt(4)\ns_barrier" ::: "memory");
    else       asm volatile("s_waitcnt vmcnt(0)\ns_barrier" ::: "memory");

    // key_rel = wk*32+kt*16+quad*4+r, query_rel = wq*32+qt*16+l16 (within this 64x64 diag tile)
    const bool skipall = diag && (wk == 1) && (wq == 0);  // keys all above queries
    const bool mdiag   = diag && (wk == wq);              // element-mask region
    // (diag && wk==0 && wq==1: fully below diagonal -> unmasked)

    if (!skipall) {
      const u16* Kc = &Ks[cur][0];
      const u16* Vc = &Vts[cur][0];
      unsigned pA[2][2], pB[2][2];               // [qt][ktL]: packed bf16 pairs
      #pragma unroll
      for (int ktL = 0; ktL < 2; ktL++) {        // two 16-key tiles of this wave's 32 keys
        const int krw = wk * 32 + ktL * 16 + l16;
        bf16x8 kf0 = *(const bf16x8*)(Kc + krw * 64 + ((0 + quad) ^ l7) * 8);
        bf16x8 kf1 = *(const bf16x8*)(Kc + krw * 64 + ((4 + quad) ^ l7) * 8);
        #pragma unroll
        for (int qt = 0; qt < 2; qt++) {
          f32x4 s0 = (f32x4){0.f, 0.f, 0.f, 0.f};
          __builtin_amdgcn_s_setprio(1);
          s0 = MFMA(kf0, qf[qt][0], s0);
          s0 = MFMA(kf1, qf[qt][1], s0);
          __builtin_amdgcn_s_setprio(0);
          if (mdiag) {
            const int qoff = (qt - ktL) * 16 + l16;   // wq==wk cancels the *32 terms
            #pragma unroll
            for (int r = 0; r < 4; r++)
              s0[r] = (quad * 4 + r > qoff) ? -1e30f : s0[r];
          }
          float p0 = __builtin_amdgcn_exp2f(s0[0]);
          float p1 = __builtin_amdgcn_exp2f(s0[1]);
          float p2 = __builtin_amdgcn_exp2f(s0[2]);
          float p3 = __builtin_amdgcn_exp2f(s0[3]);
          lsum[qt] += (p0 + p1) + (p2 + p3);
          pA[qt][ktL] = pack_bf16_trunc(p0, p1);
          pB[qt][ktL] = pack_bf16_trunc(p2, p3);
        }
      }
      // in-register P^T fragments for this wave's 32-key group
      bf16x8 pf[2];
      #pragma unroll
      for (int qt = 0; qt < 2; qt++)
        pf[qt] = quad_transpose(pA[qt][0], pB[qt][0], pA[qt][1], pB[qt][1]);
      // O^T += V^T P^T
      __builtin_amdgcn_s_setprio(1);
      #pragma unroll
      for (int co = 0; co < 4; co++) {
        const int vrw = co * 16 + l16;
        bf16x8 vf = *(const bf16x8*)(Vc + vrw * 64 + ((wk * 4 + quad) ^ (vrw & 7)) * 8);
        #pragma unroll
        for (int qt = 0; qt < 2; qt++)
          ao[qt][co] = MFMA(vf, pf[qt], ao[qt][co]);
      }
      __builtin_amdgcn_s_setprio(0);
    }
    asm volatile("s_barrier" ::: "memory");      // all waves done reading buf[cur]
  }

  // ---- epilogue: quad-reduce lsum, then cross-wave (wk) reduction of O and lsum ----
  #pragma unroll
  for (int qt = 0; qt < 2; qt++) {
    float v = lsum[qt];
    v += __shfl_xor(v, 16, 64);
    v += __shfl_xor(v, 32, 64);
    lsum[qt] = v;
  }

  // loop's final s_barrier ensures all compute done -> safe to reuse buffers as scratch
  float* red = wq ? (float*)&Vts[0][0] : (float*)&Ks[0][0];   // 8KB scratch per query-half pair
  if (wk == 1) {
    #pragma unroll
    for (int qt = 0; qt < 2; qt++)
      #pragma unroll
      for (int co = 0; co < 4; co++)
        *(f32x4*)(red + ((qt * 4 + co) * 64 + lane) * 4) = ao[qt][co];
    if (lane < 16) {
      #pragma unroll
      for (int qt = 0; qt < 2; qt++) Lbuf[wq][qt][lane] = lsum[qt];
    }
  }
  __syncthreads();
  if (wk == 0) {
    #pragma unroll
    for (int qt = 0; qt < 2; qt++) {
      float tot = lsum[qt] + Lbuf[wq][qt][l16];
      float inv = 1.0f / tot;
      int token = b * S + q0 + wq * 32 + qt * 16 + l16;
      #pragma unroll
      for (int co = 0; co < 4; co++) {
        f32x4 pr = *(const f32x4*)(red + ((qt * 4 + co) * 64 + lane) * 4);
        f32x4 sv = ao[qt][co] + pr;
        uint2 pk;
        pk.x = (unsigned)f2b(sv[0] * inv) | ((unsigned)f2b(sv[1] * inv) << 16);
        pk.y = (unsigned)f2b(sv[2] * inv) | ((unsigned)f2b(sv[3] * inv) << 16);
        *(uint2*)(ctx + (size_t)token * D + h * HD + co * 16 + quad * 4) = pk;
      }
    }
  }
}

// ---------------- output projection (m97 pattern): ctx[8192,768] x Wo^T + bias -> fp32 out
__global__ __launch_bounds__(256, 2) void out_gemm(
    const u16* __restrict__ ctx, const u16* __restrict__ wo,
    const float* __restrict__ bias, float* __restrict__ out)
{
  __shared__ __align__(16) u16 As[128 * 64];
  __shared__ __align__(16) u16 Bs[128 * 64];
  const int t = threadIdx.x;
  const int mblk = blockIdx.x, nblk = blockIdx.y;
  const int w = t >> 6, lane = t & 63, quad = lane >> 4, l16 = lane & 15;
  const int wr = w >> 1, wc = w & 1;
  const int l7 = l16 & 7;

  f32x4 acc[4][4];
  #pragma unroll
  for (int i = 0; i < 4; i++)
    #pragma unroll
    for (int j = 0; j < 4; j++) acc[i][j] = (f32x4){0.f, 0.f, 0.f, 0.f};

  int srow[4], schk[4];
  #pragma unroll
  for (int i = 0; i < 4; i++) {
    int s = i * 256 + t;
    srow[i] = s >> 3;
    schk[i] = (s & 7) ^ (srow[i] & 7);
  }
  const u16* gA = ctx + (size_t)(mblk * 128) * D;
  const u16* gB = wo  + (size_t)(nblk * 128) * D;

  for (int k0 = 0; k0 < D; k0 += 64) {
    __syncthreads();
    #pragma unroll
    for (int i = 0; i < 4; i++) {
      int s = i * 256 + t;
      cp16(gA + (size_t)srow[i] * D + k0 + schk[i] * 8, As + s * 8);
      cp16(gB + (size_t)srow[i] * D + k0 + schk[i] * 8, Bs + s * 8);
    }
    __syncthreads();
    #pragma unroll
    for (int j = 0; j < 2; j++) {
      bf16x8 af[4], bfr[4];
      #pragma unroll
      for (int mt = 0; mt < 4; mt++)
        af[mt]  = *(const bf16x8*)(As + (wr * 64 + mt * 16 + l16) * 64 + ((j * 4 + quad) ^ l7) * 8);
      #pragma unroll
      for (int nt = 0; nt < 4; nt++)
        bfr[nt] = *(const bf16x8*)(Bs + (wc * 64 + nt * 16 + l16) * 64 + ((j * 4 + quad) ^ l7) * 8);
      #pragma unroll
      for (int mt = 0; mt < 4; mt++)
        #pragma unroll
        for (int nt = 0; nt < 4; nt++)
          acc[mt][nt] = MFMA(af[mt], bfr[nt], acc[mt][nt]);
    }
  }

  #pragma unroll
  for (int mt = 0; mt < 4; mt++) {
    int m0 = mblk * 128 + wr * 64 + mt * 16 + quad * 4;
    #pragma unroll
    for (int nt = 0; nt < 4; nt++) {
      int n = nblk * 128 + wc * 64 + nt * 16 + l16;
      float bv = bias[n];
      #pragma unroll
      for (int r = 0; r < 4; r++)
        out[(size_t)(m0 + r) * D + n] = acc[mt][nt][r] + bv;
    }
  }
}

// ---------------- host launch ----------------
extern "C" void kernel_launch(void* const* d_in, const int* in_sizes, int n_in,
                              void* d_out, int out_size, void* d_ws, size_t ws_size,
                              hipStream_t stream) {
  const float* x    = (const float*)d_in[0];
  const float* wq   = (const float*)d_in[1];
  const float* wk   = (const float*)d_in[2];
  const float* wv   = (const float*)d_in[3];
  const float* wo   = (const float*)d_in[4];
  const float* bo   = (const float*)d_in[5];
  float* out = (float*)d_out;

  u16* ws = (u16*)d_ws;
  const size_t NX = (size_t)2 * S * D;      // 6291456
  const size_t NW = (size_t)D * D;          // 589824
  u16* xb  = ws;                // [8192][768]; reused as ctx after qkv_gemm consumes it
  u16* wqb = ws + NX;
  u16* wkb = wqb + NW;
  u16* wvb = wkb + NW;
  u16* wob = wvb + NW;
  u16* Qb  = wob + NW;          // [2][12][4096][64] bf16 (pre-scaled by 0.125*log2e)
  u16* Kb  = Qb + NX;           // bf16
  u16* Vt  = Kb + NX;           // [2][12][64][4096] bf16
  u16* ctx = xb;

  const int total4 = NX4 + 4 * NW4;
  castall<<<(total4 + 255) / 256, 256, 0, stream>>>(x, wq, wk, wv, wo, xb, wqb, wkb, wvb, wob);

  qkv_gemm<<<dim3(64, 6, 3), 256, 0, stream>>>(xb, wqb, wkb, wvb, Qb, Kb, Vt);
  attn<<<dim3(1536), 256, 0, stream>>>(Qb, Kb, Vt, ctx);
  out_gemm<<<dim3(64, 6), 256, 0, stream>>>(ctx, wob, bo, out);
}